// Round 1
// baseline (176.017 us; speedup 1.0000x reference)
//
#include <hip/hip_runtime.h>

// MMD RBF loss, N=8192, D=128, gamma=1, fp32 in, fp32 scalar out.
// Strategy: bf16 MFMA for the three A.B^T kernel matrices, with row norms
// computed from the SAME bf16-rounded data so diagonal dist == 0 +- 1e-4.
// Self-pairs (xx, yy) compute only upper-triangle tiles with weight 2.

#define N_PTS 8192
#define DCOLS 128
#define TILE 128
#define TJ 64          // 8192/128 tiles per side
#define NSELF 2080     // 64*65/2
#define NJOBS 8256     // 2*2080 + 4096
#define LOG2E 1.4426950408889634f

typedef __attribute__((ext_vector_type(8))) short short8;   // 8 bf16 = 4 VGPRs
typedef __attribute__((ext_vector_type(4))) float floatx4;  // MFMA acc
typedef unsigned int u32;
typedef unsigned short u16;

#if __has_builtin(__builtin_amdgcn_exp2f)
#define EXP2(x) __builtin_amdgcn_exp2f(x)
#else
#define EXP2(x) exp2f(x)
#endif

__device__ __forceinline__ u16 f32_to_bf16(float f) {
  u32 u = __float_as_uint(f);
  u32 r = (u + 0x7fffu + ((u >> 16) & 1u)) >> 16;  // RNE
  return (u16)r;
}

__device__ __forceinline__ void gl_lds16(const u16* g, u16* l) {
  // async global->LDS, 16B/lane; LDS dest = uniform base + lane*16
  __builtin_amdgcn_global_load_lds(
      (const __attribute__((address_space(1))) u32*)g,
      (__attribute__((address_space(3))) u32*)l, 16, 0, 0);
}

// ---- prep: fp32 -> bf16 (RNE) + per-row  d = -gamma*log2e*sum(xb^2)  ----
__global__ void prep_kernel(const float* __restrict__ x, const float* __restrict__ y,
                            u32* __restrict__ xb, u32* __restrict__ yb,
                            float* __restrict__ da, float* __restrict__ db) {
  int wid = threadIdx.x >> 6;
  int lane = threadIdx.x & 63;
  int row = blockIdx.x * 4 + wid;  // 0..16383
  const float* src;
  u32* dst;
  float* dn;
  int r;
  if (row < N_PTS) { src = x; dst = xb; dn = da; r = row; }
  else             { src = y; dst = yb; dn = db; r = row - N_PTS; }
  float2 v = ((const float2*)(src + (size_t)r * DCOLS))[lane];
  u16 b0 = f32_to_bf16(v.x), b1 = f32_to_bf16(v.y);
  float f0 = __uint_as_float((u32)b0 << 16);
  float f1 = __uint_as_float((u32)b1 << 16);
  float p = f0 * f0 + f1 * f1;
  dst[(size_t)r * 64 + lane] = (u32)b0 | ((u32)b1 << 16);
#pragma unroll
  for (int off = 32; off; off >>= 1) p += __shfl_down(p, off, 64);
  if (lane == 0) dn[r] = -LOG2E * p;  // gamma = 1
}

// ---- main: one 128x128 tile per block; sum of exp2(c1*s + d_m + d_n) ----
__global__ __launch_bounds__(256) void mmd_kernel(
    const u16* __restrict__ xb, const u16* __restrict__ yb,
    const float* __restrict__ da, const float* __restrict__ db,
    float* __restrict__ S) {
  // XOR-swizzled tiles: 16B block b of row r stored at slot (b ^ (r&15)).
  __shared__ u16 At[TILE * DCOLS];  // 32 KB
  __shared__ u16 Bt[TILE * DCOLS];  // 32 KB  (total 64 KB -> 2 blocks/CU)

  int t = blockIdx.x;
  int pair, rr, cc;
  float w;
  const u16 *Aab, *Bab;
  const float *dA, *dB;
  if (t < 2 * NSELF) {
    pair = (t < NSELF) ? 0 : 1;
    int tt = (t < NSELF) ? t : t - NSELF;
    int r = 0;
    while (tt >= (TJ - r)) { tt -= (TJ - r); r++; }  // upper-tri decode
    rr = r; cc = r + tt;
    if (pair == 0) { Aab = xb; Bab = xb; dA = da; dB = da; }
    else           { Aab = yb; Bab = yb; dA = db; dB = db; }
    w = (rr == cc) ? 1.0f : 2.0f;
  } else {
    pair = 2;
    int q = t - 2 * NSELF;
    rr = q >> 6; cc = q & 63;
    Aab = xb; Bab = yb; dA = da; dB = db;
    w = 1.0f;
  }

  int tid = threadIdx.x;
  int wid = tid >> 6, lane = tid & 63;
  int quad = lane >> 4, l15 = lane & 15;

  // ---- stage both tiles (waves 0,1 -> A; waves 2,3 -> B), swizzled ----
  {
    const u16* gsrc = (wid < 2) ? Aab + (size_t)rr * (TILE * DCOLS)
                                : Bab + (size_t)cc * (TILE * DCOLS);
    u16* ldst = (wid < 2) ? At : Bt;
    int ch0 = (wid & 1) * 16;
#pragma unroll
    for (int ch = ch0; ch < ch0 + 16; ch++) {
      int lrow = ch * 4 + quad;               // local row this lane feeds
      int bsw = l15 ^ (lrow & 15);            // inverse swizzle on global side
      gl_lds16(gsrc + lrow * DCOLS + bsw * 8, ldst + ch * 512);
    }
  }

  // norm terms for this wave's 64x64 quadrant (independent VMEM loads)
  int mbase = (wid >> 1) * 64, nbase = (wid & 1) * 64;
  float dam[16], dbn[4];
  {
    const float* dAr = dA + rr * TILE + mbase;
#pragma unroll
    for (int mi = 0; mi < 4; mi++)
#pragma unroll
      for (int v = 0; v < 4; v++) dam[mi * 4 + v] = dAr[mi * 16 + quad * 4 + v];
    const float* dBr = dB + cc * TILE + nbase;
#pragma unroll
    for (int ni = 0; ni < 4; ni++) dbn[ni] = dBr[ni * 16 + l15];
  }

  __builtin_amdgcn_s_waitcnt(0);  // drain global_load_lds
  __syncthreads();

  // ---- K-loop: 4 steps of 16x16x32, 4x4 frags per wave ----
  floatx4 zero = {0.f, 0.f, 0.f, 0.f};
  floatx4 acc[4][4];
#pragma unroll
  for (int mi = 0; mi < 4; mi++)
#pragma unroll
    for (int ni = 0; ni < 4; ni++) acc[mi][ni] = zero;

#pragma unroll
  for (int ks = 0; ks < 4; ks++) {
    short8 af[4], bf[4];
    int slot = (ks * 4 + quad) ^ l15;  // row&15 == l15 for all frag rows
#pragma unroll
    for (int mi = 0; mi < 4; mi++) {
      int row = mbase + mi * 16 + l15;
      af[mi] = *(const short8*)(At + row * DCOLS + slot * 8);
    }
#pragma unroll
    for (int ni = 0; ni < 4; ni++) {
      int row = nbase + ni * 16 + l15;
      bf[ni] = *(const short8*)(Bt + row * DCOLS + slot * 8);
    }
#pragma unroll
    for (int mi = 0; mi < 4; mi++)
#pragma unroll
      for (int ni = 0; ni < 4; ni++)
        acc[mi][ni] = __builtin_amdgcn_mfma_f32_16x16x32_bf16(af[mi], bf[ni],
                                                              acc[mi][ni], 0, 0, 0);
  }

  // ---- epilogue: exp2(c1*s + d_m + d_n), thread-local fp32 sum ----
  const float c1 = 2.0f * LOG2E;
  float tsum = 0.f;
#pragma unroll
  for (int mi = 0; mi < 4; mi++)
#pragma unroll
    for (int ni = 0; ni < 4; ni++)
#pragma unroll
      for (int v = 0; v < 4; v++) {
        float arg = fmaf(c1, acc[mi][ni][v], dam[mi * 4 + v] + dbn[ni]);
        tsum += EXP2(arg);
      }

#pragma unroll
  for (int off = 32; off; off >>= 1) tsum += __shfl_down(tsum, off, 64);

  __syncthreads();                 // all waves done reading LDS; reuse At
  float* red = (float*)At;
  if (lane == 0) red[wid] = tsum;
  __syncthreads();
  if (tid == 0) {
    float tot = (red[0] + red[1] + red[2] + red[3]) * w;
    atomicAdd(&S[pair], tot);
  }
}

__global__ void final_kernel(const float* __restrict__ S, float* __restrict__ out) {
  out[0] = (S[0] + S[1] - 2.0f * S[2]) *
           (1.0f / ((float)N_PTS * (float)N_PTS));
}

extern "C" void kernel_launch(void* const* d_in, const int* in_sizes, int n_in,
                              void* d_out, int out_size, void* d_ws, size_t ws_size,
                              hipStream_t stream) {
  const float* x = (const float*)d_in[0];
  const float* y = (const float*)d_in[1];
  char* ws = (char*)d_ws;
  float* S = (float*)ws;                                   // 3 floats
  u32* xb = (u32*)(ws + 256);                              // 2 MB bf16
  u32* yb = (u32*)(ws + 256 + 2097152);                    // 2 MB bf16
  float* da = (float*)(ws + 256 + 2 * 2097152);            // 32 KB
  float* db = (float*)(ws + 256 + 2 * 2097152 + 32768);    // 32 KB

  hipMemsetAsync(S, 0, 16, stream);
  prep_kernel<<<4096, 256, 0, stream>>>(x, y, xb, yb, da, db);
  mmd_kernel<<<NJOBS, 256, 0, stream>>>((const u16*)xb, (const u16*)yb, da, db, S);
  final_kernel<<<1, 1, 0, stream>>>(S, (float*)d_out);
}

// Round 2
// 128.998 us; speedup vs baseline: 1.3645x; 1.3645x over previous
//
#include <hip/hip_runtime.h>

// MMD RBF loss, N=8192, D=128, gamma=1, fp32 in, fp32 scalar out.
// R2: strip-pipelined MFMA. Per block: run of tiles sharing the A row-block.
// A-fragments in registers (loaded once per strip, direct from global);
// B tiles ping-pong in LDS via global_load_lds, staged one tile ahead.
// Epilogue thresholded: off-diagonal args are <= -90, exp computed only for
// groups with any arg > -40 (dropped mass < 1e-10 of the answer).

#define N_PTS 8192
#define DCOLS 128
#define TILE 128
#define TJ 64          // 8192/128 tiles per side
#define NSELF 2080     // 64*65/2
#define NJOBS 8256     // 2*2080 + 4096
#define NBLOCKS 512
#define LOG2E 1.4426950408889634f
#define THRESH -40.0f

typedef __attribute__((ext_vector_type(8))) short short8;   // 8 bf16 = 4 VGPRs
typedef __attribute__((ext_vector_type(4))) float floatx4;  // MFMA acc
typedef unsigned int u32;
typedef unsigned short u16;

#if __has_builtin(__builtin_amdgcn_exp2f)
#define EXP2(x) __builtin_amdgcn_exp2f(x)
#else
#define EXP2(x) exp2f(x)
#endif

__device__ __forceinline__ u16 f32_to_bf16(float f) {
  u32 u = __float_as_uint(f);
  u32 r = (u + 0x7fffu + ((u >> 16) & 1u)) >> 16;  // RNE
  return (u16)r;
}

__device__ __forceinline__ void gl_lds16(const u16* g, u16* l) {
  // async global->LDS, 16B/lane; LDS dest = uniform base + lane*16
  __builtin_amdgcn_global_load_lds(
      (const __attribute__((address_space(1))) u32*)g,
      (__attribute__((address_space(3))) u32*)l, 16, 0, 0);
}

// ---- prep: fp32 -> bf16 (RNE) + per-row d = -log2e*sum(xb^2); zero S/cnt ----
__global__ void prep_kernel(const float* __restrict__ x, const float* __restrict__ y,
                            u32* __restrict__ xb, u32* __restrict__ yb,
                            float* __restrict__ da, float* __restrict__ db,
                            u32* __restrict__ Sz) {
  if (blockIdx.x == 0 && threadIdx.x < 4) Sz[threadIdx.x] = 0;  // S[0..2], cnt
  int wid = threadIdx.x >> 6;
  int lane = threadIdx.x & 63;
  int row = blockIdx.x * 4 + wid;  // 0..16383
  const float* src;
  u32* dst;
  float* dn;
  int r;
  if (row < N_PTS) { src = x; dst = xb; dn = da; r = row; }
  else             { src = y; dst = yb; dn = db; r = row - N_PTS; }
  float2 v = ((const float2*)(src + (size_t)r * DCOLS))[lane];
  u16 b0 = f32_to_bf16(v.x), b1 = f32_to_bf16(v.y);
  float f0 = __uint_as_float((u32)b0 << 16);
  float f1 = __uint_as_float((u32)b1 << 16);
  float p = f0 * f0 + f1 * f1;
  dst[(size_t)r * 64 + lane] = (u32)b0 | ((u32)b1 << 16);
#pragma unroll
  for (int off = 32; off; off >>= 1) p += __shfl_down(p, off, 64);
  if (lane == 0) dn[r] = -LOG2E * p;
}

struct Job { int pair, rr, cc; };

__device__ __forceinline__ Job decode_job(int t) {
  Job jb;
  if (t < 2 * NSELF) {
    jb.pair = (t < NSELF) ? 0 : 1;
    int tt = t - jb.pair * NSELF;
    int r = 0;
    while (tt >= TJ - r) { tt -= TJ - r; r++; }
    jb.rr = r; jb.cc = r + tt;
  } else {
    int q = t - 2 * NSELF;
    jb.pair = 2; jb.rr = q >> 6; jb.cc = q & 63;
  }
  return jb;
}

__device__ __forceinline__ Job next_job(Job c) {
  Job n = c;
  if (c.pair == 2) {
    if (c.cc == 63) { n.rr++; n.cc = 0; } else n.cc++;
  } else {
    if (c.cc == 63) {
      if (c.rr == 63) { n.pair++; n.rr = 0; n.cc = 0; }
      else { n.rr++; n.cc = n.rr; }
    } else n.cc++;
  }
  return n;
}

__device__ __forceinline__ void pair_ptrs(int pair, const u16* xb, const u16* yb,
                                          const float* da, const float* db,
                                          const u16*& A, const u16*& B,
                                          const float*& dA, const float*& dB) {
  A = (pair == 1) ? yb : xb;
  B = (pair == 0) ? xb : yb;
  dA = (pair == 1) ? db : da;
  dB = (pair == 0) ? da : db;
}

__device__ __forceinline__ void stage_tile(const u16* gsrc, u16* ldst,
                                           int wid, int quad, int l15) {
#pragma unroll
  for (int i = 0; i < 8; i++) {
    int ch = wid * 8 + i;
    int lrow = ch * 4 + quad;                // local row this lane feeds
    int bsw = l15 ^ (lrow & 15);             // inverse swizzle on global side
    gl_lds16(gsrc + lrow * DCOLS + bsw * 8, ldst + ch * 512);
  }
}

__device__ __forceinline__ void load_afrags(const u16* gA, const float* gdA, int rr,
                                            int mbase, int quad, int l15,
                                            short8 afr[4][4], float dam[16]) {
  const u16* base = gA + (size_t)rr * (TILE * DCOLS);
#pragma unroll
  for (int ks = 0; ks < 4; ks++)
#pragma unroll
    for (int mi = 0; mi < 4; mi++)
      afr[ks][mi] = *(const short8*)(base + (mbase + mi * 16 + l15) * DCOLS +
                                     ks * 32 + quad * 8);
  const float* dr = gdA + rr * TILE + mbase;
#pragma unroll
  for (int mi = 0; mi < 4; mi++)
#pragma unroll
    for (int v = 0; v < 4; v++) dam[mi * 4 + v] = dr[mi * 16 + quad * 4 + v];
}

__global__ __launch_bounds__(256, 2) void mmd_kernel(
    const u16* __restrict__ xb, const u16* __restrict__ yb,
    const float* __restrict__ da, const float* __restrict__ db,
    float* __restrict__ S, u32* __restrict__ cnt, float* __restrict__ out) {
  __shared__ u16 Bt[2][TILE * DCOLS];  // 2 x 32 KB ping-pong

  int tid = threadIdx.x;
  int wid = tid >> 6, lane = tid & 63;
  int quad = lane >> 4, l15 = lane & 15;
  int mbase = (wid >> 1) * 64, nbase = (wid & 1) * 64;

  int start = (blockIdx.x * NJOBS) >> 9;        // NBLOCKS = 512
  int end = ((blockIdx.x + 1) * NJOBS) >> 9;

  Job cur = decode_job(start);
  const u16 *cA, *cB;
  const float *cdA, *cdB;
  pair_ptrs(cur.pair, xb, yb, da, db, cA, cB, cdA, cdB);

  short8 afr[4][4];
  float dam[16];
  load_afrags(cA, cdA, cur.rr, mbase, quad, l15, afr, dam);
  stage_tile(cB + (size_t)cur.cc * (TILE * DCOLS), &Bt[0][0], wid, quad, l15);
  __syncthreads();  // implicit vmcnt(0) drain: tile 0 staged, afr loaded

  const float c1 = 2.0f * LOG2E;
  float tsum = 0.f;
  int p = 0;

  for (int j = start; j < end; j++) {
    bool hasNext = (j + 1 < end);
    Job nxt;
    const u16 *nA = cA, *nB = cB;
    const float *ndA = cdA, *ndB = cdB;

    // dbn (cur) FIRST so its waitcnt doesn't drag in next-tile staging
    float dbn[4];
    {
      const float* dr = cdB + cur.cc * TILE + nbase;
#pragma unroll
      for (int ni = 0; ni < 4; ni++) dbn[ni] = dr[ni * 16 + l15];
    }

    if (hasNext) {
      nxt = next_job(cur);
      pair_ptrs(nxt.pair, xb, yb, da, db, nA, nB, ndA, ndB);
      stage_tile(nB + (size_t)nxt.cc * (TILE * DCOLS), &Bt[p ^ 1][0], wid, quad, l15);
    }

    // ---- compute tile j from Bt[p]: 4 K-steps, 4x4 frags ----
    floatx4 acc[4][4];
    floatx4 zero = {0.f, 0.f, 0.f, 0.f};
#pragma unroll
    for (int mi = 0; mi < 4; mi++)
#pragma unroll
      for (int ni = 0; ni < 4; ni++) acc[mi][ni] = zero;

#pragma unroll
    for (int ks = 0; ks < 4; ks++) {
      short8 bf[4];
      int slot = (ks * 4 + quad) ^ l15;
#pragma unroll
      for (int ni = 0; ni < 4; ni++) {
        int row = nbase + ni * 16 + l15;
        bf[ni] = *(const short8*)(&Bt[p][row * DCOLS + slot * 8]);
      }
#pragma unroll
      for (int mi = 0; mi < 4; mi++)
#pragma unroll
        for (int ni = 0; ni < 4; ni++)
          acc[mi][ni] = __builtin_amdgcn_mfma_f32_16x16x32_bf16(
              afr[ks][mi], bf[ni], acc[mi][ni], 0, 0, 0);
    }

    // ---- thresholded epilogue ----
    float w = (cur.pair < 2 && cur.rr != cur.cc) ? 2.0f : 1.0f;
#pragma unroll
    for (int mi = 0; mi < 4; mi++) {
#pragma unroll
      for (int ni = 0; ni < 4; ni++) {
        float tv0 = fmaf(c1, acc[mi][ni][0], dam[mi * 4 + 0]);
        float tv1 = fmaf(c1, acc[mi][ni][1], dam[mi * 4 + 1]);
        float tv2 = fmaf(c1, acc[mi][ni][2], dam[mi * 4 + 2]);
        float tv3 = fmaf(c1, acc[mi][ni][3], dam[mi * 4 + 3]);
        float mx = fmaxf(fmaxf(tv0, tv1), fmaxf(tv2, tv3)) + dbn[ni];
        if (__any(mx > THRESH)) {
          float e = EXP2(tv0 + dbn[ni]) + EXP2(tv1 + dbn[ni]) +
                    EXP2(tv2 + dbn[ni]) + EXP2(tv3 + dbn[ni]);
          tsum = fmaf(w, e, tsum);
        }
      }
    }

    // flush on pair boundary / strip end (<=3 atomics per wave per block)
    bool flush = !hasNext || (nxt.pair != cur.pair);
    if (flush) {
      float r = tsum;
#pragma unroll
      for (int off = 32; off; off >>= 1) r += __shfl_down(r, off, 64);
      if (lane == 0) atomicAdd(&S[cur.pair], r);
      tsum = 0.f;
    }

    // A row-block change: reload register fragments (rare, <=2 per block)
    if (hasNext && (nxt.pair != cur.pair || nxt.rr != cur.rr))
      load_afrags(nA, ndA, nxt.rr, mbase, quad, l15, afr, dam);

    __syncthreads();  // drains staging of tile j+1; releases Bt[p]
    p ^= 1;
    if (hasNext) { cur = nxt; cA = nA; cB = nB; cdA = ndA; cdB = ndB; }
  }

  // ---- last block combines ----
  __syncthreads();
  if (tid == 0) {
    __threadfence();
    u32 old = atomicAdd(cnt, 1u);
    if (old == (u32)(NBLOCKS - 1)) {
      float s0 = atomicAdd(&S[0], 0.0f);
      float s1 = atomicAdd(&S[1], 0.0f);
      float s2 = atomicAdd(&S[2], 0.0f);
      out[0] = (s0 + s1 - 2.0f * s2) * (1.0f / ((float)N_PTS * (float)N_PTS));
    }
  }
}

extern "C" void kernel_launch(void* const* d_in, const int* in_sizes, int n_in,
                              void* d_out, int out_size, void* d_ws, size_t ws_size,
                              hipStream_t stream) {
  const float* x = (const float*)d_in[0];
  const float* y = (const float*)d_in[1];
  char* ws = (char*)d_ws;
  float* S = (float*)ws;                                   // S[0..2], cnt
  u32* cnt = (u32*)ws + 3;
  u32* xb = (u32*)(ws + 256);                              // 2 MB bf16
  u32* yb = (u32*)(ws + 256 + 2097152);                    // 2 MB bf16
  float* da = (float*)(ws + 256 + 2 * 2097152);            // 32 KB
  float* db = (float*)(ws + 256 + 2 * 2097152 + 32768);    // 32 KB

  prep_kernel<<<4096, 256, 0, stream>>>(x, y, xb, yb, da, db, (u32*)ws);
  mmd_kernel<<<NBLOCKS, 256, 0, stream>>>((const u16*)xb, (const u16*)yb,
                                          da, db, S, cnt, (float*)d_out);
}